// Round 1
// baseline (612.864 us; speedup 1.0000x reference)
//
#include <hip/hip_runtime.h>
#include <cstdint>
#include <cstddef>

#define D_DIM 128

typedef __attribute__((ext_vector_type(8))) __bf16 bf16x8;
typedef __attribute__((ext_vector_type(4))) float f32x4;

__device__ __forceinline__ unsigned short f2bf(float f) {
    unsigned u = __builtin_bit_cast(unsigned, f);
    u += 0x7FFFu + ((u >> 16) & 1u);   // round-to-nearest-even (no NaN in data)
    return (unsigned short)(u >> 16);
}
__device__ __forceinline__ float bf2f(unsigned short h) {
    unsigned u = ((unsigned)h) << 16;
    return __builtin_bit_cast(float, u);
}

// ---------------------------------------------------------------------------
// Prepass: fp32 -> bf16 conversion + squared norms of the bf16-rounded rows.
// One wave per row (128 floats): lane loads float2, packs 2 bf16, shuffle-reduce.
// ---------------------------------------------------------------------------
__global__ __launch_bounds__(256) void prep_kernel(
    const float* __restrict__ x, const float* __restrict__ w,
    unsigned short* __restrict__ xb, unsigned short* __restrict__ wb,
    float* __restrict__ xsq, float* __restrict__ wsq,
    int n_rows_x, int n_rows_w)
{
    const int wave = threadIdx.x >> 6;
    const int lane = threadIdx.x & 63;
    int row = blockIdx.x * 4 + wave;
    const float* src; unsigned short* dst; float* nrm; int r;
    if (row < n_rows_x) { src = x; dst = xb; nrm = xsq; r = row; }
    else {
        r = row - n_rows_x;
        if (r >= n_rows_w) return;
        src = w; dst = wb; nrm = wsq;
    }
    const float2* srow = reinterpret_cast<const float2*>(src + (size_t)r * D_DIM);
    float2 v = srow[lane];
    unsigned short b0 = f2bf(v.x), b1 = f2bf(v.y);
    float f0 = bf2f(b0), f1 = bf2f(b1);
    unsigned pack = (unsigned)b0 | ((unsigned)b1 << 16);
    reinterpret_cast<unsigned*>(dst + (size_t)r * D_DIM)[lane] = pack;
    float s = f0 * f0 + f1 * f1;
    #pragma unroll
    for (int off = 32; off > 0; off >>= 1) s += __shfl_xor(s, off, 64);
    if (lane == 0) nrm[r] = s;
}

// ---------------------------------------------------------------------------
// GEMM: out[n,c] = xsq[n] + wsq[c] - 2 * <x[n,:], w[c,:]>   (bf16 MFMA)
// 128x128 tile / block (256 thr = 4 waves, each wave a 64x64 subtile).
// K=128 staged once into LDS via global_load_lds width=16 (m97 pattern).
// ---------------------------------------------------------------------------
__global__ __launch_bounds__(256, 2) void rbf_gemm(
    const unsigned short* __restrict__ xb, const unsigned short* __restrict__ wb,
    const float* __restrict__ xsq, const float* __restrict__ wsq,
    float* __restrict__ out, int C_total)
{
    __shared__ __align__(16) unsigned short As[128 * 128];  // 32 KB
    __shared__ __align__(16) unsigned short Bs[128 * 128];  // 32 KB

    const int tid    = threadIdx.x;
    const int wave   = tid >> 6;
    const int lane   = tid & 63;
    const int lane16 = lane & 15;
    const int quad   = lane >> 4;

    const long c0 = (long)blockIdx.x * 128;   // c-tile (fastest -> x-tile L2/L3 reuse)
    const long m0 = (long)blockIdx.y * 128;

    // --- stage x-tile and w-tile: 32 chunks of 1 KiB each (4 rows/chunk) ---
    {
        const unsigned short* gA = xb + (size_t)m0 * D_DIM;
        const unsigned short* gB = wb + (size_t)c0 * D_DIM;
        #pragma unroll
        for (int i = 0; i < 8; ++i) {
            const int chunk = wave * 8 + i;           // 0..31
            const unsigned short* ga = gA + chunk * 512 + lane * 8;
            __builtin_amdgcn_global_load_lds(
                (const __attribute__((address_space(1))) unsigned*)ga,
                (__attribute__((address_space(3))) unsigned*)(As + chunk * 512),
                16, 0, 0);
        }
        #pragma unroll
        for (int i = 0; i < 8; ++i) {
            const int chunk = wave * 8 + i;
            const unsigned short* gb = gB + chunk * 512 + lane * 8;
            __builtin_amdgcn_global_load_lds(
                (const __attribute__((address_space(1))) unsigned*)gb,
                (__attribute__((address_space(3))) unsigned*)(Bs + chunk * 512),
                16, 0, 0);
        }
    }
    __syncthreads();   // compiler emits vmcnt(0) drain before s_barrier

    const int wm = (wave & 1) * 64;
    const int wc = (wave >> 1) * 64;

    f32x4 acc[4][4];
    #pragma unroll
    for (int i = 0; i < 4; ++i)
        #pragma unroll
        for (int j = 0; j < 4; ++j)
            acc[i][j] = (f32x4){0.f, 0.f, 0.f, 0.f};

    // A-operand layout: lane holds A[m = lane&15][k = quad*8 + j], j=0..7
    #pragma unroll
    for (int kk = 0; kk < 128; kk += 32) {
        bf16x8 a[4], b[4];
        #pragma unroll
        for (int mt = 0; mt < 4; ++mt)
            a[mt] = *reinterpret_cast<const bf16x8*>(
                &As[(wm + mt * 16 + lane16) * 128 + kk + quad * 8]);
        #pragma unroll
        for (int ct = 0; ct < 4; ++ct)
            b[ct] = *reinterpret_cast<const bf16x8*>(
                &Bs[(wc + ct * 16 + lane16) * 128 + kk + quad * 8]);
        #pragma unroll
        for (int mt = 0; mt < 4; ++mt)
            #pragma unroll
            for (int ct = 0; ct < 4; ++ct)
                acc[mt][ct] = __builtin_amdgcn_mfma_f32_16x16x32_bf16(
                    a[mt], b[ct], acc[mt][ct], 0, 0, 0);
    }

    // --- epilogue: C/D layout col = lane&15, row = quad*4 + reg ---
    float wsqv[4];
    #pragma unroll
    for (int ct = 0; ct < 4; ++ct)
        wsqv[ct] = wsq[c0 + wc + ct * 16 + lane16];

    #pragma unroll
    for (int mt = 0; mt < 4; ++mt) {
        const long rbase = m0 + wm + mt * 16 + quad * 4;
        float xs[4];
        #pragma unroll
        for (int i = 0; i < 4; ++i) xs[i] = xsq[rbase + i];
        #pragma unroll
        for (int ct = 0; ct < 4; ++ct) {
            const long col = c0 + wc + ct * 16 + lane16;
            #pragma unroll
            for (int i = 0; i < 4; ++i) {
                out[(rbase + i) * (long)C_total + col] =
                    xs[i] + wsqv[ct] - 2.0f * acc[mt][ct][i];
            }
        }
    }
}

extern "C" void kernel_launch(void* const* d_in, const int* in_sizes, int n_in,
                              void* d_out, int out_size, void* d_ws, size_t ws_size,
                              hipStream_t stream) {
    const float* x = (const float*)d_in[0];
    const float* w = (const float*)d_in[1];
    float* out = (float*)d_out;

    const int N = in_sizes[0] / D_DIM;   // 131072
    const int C = in_sizes[1] / D_DIM;   // 1024

    // workspace layout: xb bf16[N*128] | wb bf16[C*128] | xsq f32[N] | wsq f32[C]
    unsigned short* xb = (unsigned short*)d_ws;
    unsigned short* wb = xb + (size_t)N * D_DIM;
    float* xsq = (float*)(wb + (size_t)C * D_DIM);
    float* wsq = xsq + N;

    const int rows = N + C;
    prep_kernel<<<(rows + 3) / 4, 256, 0, stream>>>(x, w, xb, wb, xsq, wsq, N, C);

    dim3 grid(C / 128, N / 128);   // (8, 1024)
    rbf_gemm<<<grid, 256, 0, stream>>>(xb, wb, xsq, wsq, out, C);
}